// Round 1
// baseline (418.664 us; speedup 1.0000x reference)
//
#include <hip/hip_runtime.h>
#include <hip/hip_bf16.h>

// ARAPLoss: out[b] = mean_e | ||x[b,dst]-x[b,src]||^2 - ||dx[b,dst]-dx[b,src]||^2 |
// B=8, NV=100000, E = in_sizes[2] (~1.19M directed deduplicated edges).
// Gather-bound: data (19.2MB) fits LLC; edges sorted by src -> src gathers ~sequential.

#define NBATCH 8
#define NVERT 100000

__global__ __launch_bounds__(256) void arap_edge_kernel(
    const float* __restrict__ dx, const float* __restrict__ x,
    const int* __restrict__ src, const int* __restrict__ dst,
    float* __restrict__ out, int E, float invE)
{
    float acc[NBATCH];
#pragma unroll
    for (int b = 0; b < NBATCH; ++b) acc[b] = 0.0f;

    const int stride = gridDim.x * blockDim.x;
    const size_t bstride = (size_t)NVERT * 3;  // floats per batch slice

    for (int e = blockIdx.x * blockDim.x + threadIdx.x; e < E; e += stride) {
        const int s = src[e] * 3;
        const int d = dst[e] * 3;
#pragma unroll
        for (int b = 0; b < NBATCH; ++b) {
            const float* __restrict__ xb  = x  + b * bstride;
            const float* __restrict__ dxb = dx + b * bstride;
            float ex0 = xb[d]     - xb[s];
            float ex1 = xb[d + 1] - xb[s + 1];
            float ex2 = xb[d + 2] - xb[s + 2];
            float ed0 = dxb[d]     - dxb[s];
            float ed1 = dxb[d + 1] - dxb[s + 1];
            float ed2 = dxb[d + 2] - dxb[s + 2];
            float diffx  = ex0 * ex0 + ex1 * ex1 + ex2 * ex2;
            float diffdx = ed0 * ed0 + ed1 * ed1 + ed2 * ed2;
            acc[b] += fabsf(diffx - diffdx);
        }
    }

    // wave (64-lane) shuffle reduction per batch accumulator
#pragma unroll
    for (int b = 0; b < NBATCH; ++b) {
#pragma unroll
        for (int off = 32; off > 0; off >>= 1)
            acc[b] += __shfl_down(acc[b], off, 64);
    }

    __shared__ float red[4][NBATCH];  // 256 threads = 4 waves
    const int wave = threadIdx.x >> 6;
    const int lane = threadIdx.x & 63;
    if (lane == 0) {
#pragma unroll
        for (int b = 0; b < NBATCH; ++b) red[wave][b] = acc[b];
    }
    __syncthreads();
    if (threadIdx.x == 0) {
#pragma unroll
        for (int b = 0; b < NBATCH; ++b) {
            float t = red[0][b] + red[1][b] + red[2][b] + red[3][b];
            atomicAdd(&out[b], t * invE);
        }
    }
}

extern "C" void kernel_launch(void* const* d_in, const int* in_sizes, int n_in,
                              void* d_out, int out_size, void* d_ws, size_t ws_size,
                              hipStream_t stream) {
    const float* dx = (const float*)d_in[0];
    const float* x  = (const float*)d_in[1];
    const int* edge_src = (const int*)d_in[2];
    const int* edge_dst = (const int*)d_in[3];
    float* out = (float*)d_out;

    const int E = in_sizes[2];
    const float invE = 1.0f / (float)E;

    // d_out is poisoned (0xAA) before every timed launch; zero it for the atomics.
    hipMemsetAsync(d_out, 0, NBATCH * sizeof(float), stream);

    const int threads = 256;
    int blocks = (E + threads - 1) / threads;
    if (blocks > 2048) blocks = 2048;  // grid-stride; 8 blocks/CU worth of work queue

    arap_edge_kernel<<<blocks, threads, 0, stream>>>(dx, x, edge_src, edge_dst,
                                                     out, E, invE);
}

// Round 2
// 144.761 us; speedup vs baseline: 2.8921x; 2.8921x over previous
//
#include <hip/hip_runtime.h>
#include <hip/hip_bf16.h>

// ARAPLoss: out[b] = mean_e | ||x[b,dst]-x[b,src]||^2 - ||dx[b,dst]-dx[b,src]||^2 |
// B=8, NV=100000, E ~ 1.19M directed dedup edges.
//
// R1 lesson: batch-inner loop -> 19.2MB working set per XCD -> L2 thrash,
// FETCH_SIZE 1.03GB, 345us. Fix: (a) pack (x,dx) into 32B records in d_ws,
// (b) one batch per block with batch = blockIdx&7 so each XCD (round-robin
// dispatch) sees one 3.2MB batch slice that fits its 4MiB L2.

#define NBATCH 8
#define NVERT 100000

// ---- pre-pass: rec[b][v] = {x0,x1,x2,dx0} {dx1,dx2,0,0} (32B, aligned) ----
__global__ __launch_bounds__(256) void arap_pack_kernel(
    const float* __restrict__ dx, const float* __restrict__ x,
    float4* __restrict__ recs)
{
    int t = blockIdx.x * blockDim.x + threadIdx.x;
    if (t >= NBATCH * NVERT) return;
    int b = t / NVERT;
    int v = t - b * NVERT;
    size_t src = (size_t)b * NVERT * 3 + (size_t)v * 3;
    float x0 = x[src], x1 = x[src + 1], x2 = x[src + 2];
    float d0 = dx[src], d1 = dx[src + 1], d2 = dx[src + 2];
    size_t r = (size_t)t * 2;
    recs[r]     = make_float4(x0, x1, x2, d0);
    recs[r + 1] = make_float4(d1, d2, 0.0f, 0.0f);
}

// ---- main: one batch per block (blockIdx&7 -> XCD affinity) ----
__global__ __launch_bounds__(256) void arap_edge_packed_kernel(
    const float4* __restrict__ recs,
    const int* __restrict__ src, const int* __restrict__ dst,
    float* __restrict__ out, int E, float invE)
{
    const int b = blockIdx.x & 7;
    const int chunk = blockIdx.x >> 3;
    const int nchunk = gridDim.x >> 3;
    const int stride = nchunk * blockDim.x;
    const float4* __restrict__ rb = recs + (size_t)b * NVERT * 2;

    float acc = 0.0f;
    for (int e = chunk * blockDim.x + threadIdx.x; e < E; e += stride) {
        const int s = src[e] * 2;
        const int d = dst[e] * 2;
        float4 s0 = rb[s];
        float4 s1 = rb[s + 1];
        float4 d0 = rb[d];
        float4 d1 = rb[d + 1];
        float ex0 = d0.x - s0.x;
        float ex1 = d0.y - s0.y;
        float ex2 = d0.z - s0.z;
        float ed0 = d0.w - s0.w;
        float ed1 = d1.x - s1.x;
        float ed2 = d1.y - s1.y;
        float diffx  = ex0 * ex0 + ex1 * ex1 + ex2 * ex2;
        float diffdx = ed0 * ed0 + ed1 * ed1 + ed2 * ed2;
        acc += fabsf(diffx - diffdx);
    }

    // 64-lane wave reduction
#pragma unroll
    for (int off = 32; off > 0; off >>= 1)
        acc += __shfl_down(acc, off, 64);

    __shared__ float red[4];
    const int wave = threadIdx.x >> 6;
    const int lane = threadIdx.x & 63;
    if (lane == 0) red[wave] = acc;
    __syncthreads();
    if (threadIdx.x == 0) {
        float t = red[0] + red[1] + red[2] + red[3];
        atomicAdd(&out[b], t * invE);
    }
}

// ---- fallback (R1 kernel) if d_ws is too small for the packed records ----
__global__ __launch_bounds__(256) void arap_edge_kernel(
    const float* __restrict__ dx, const float* __restrict__ x,
    const int* __restrict__ src, const int* __restrict__ dst,
    float* __restrict__ out, int E, float invE)
{
    float acc[NBATCH];
#pragma unroll
    for (int b = 0; b < NBATCH; ++b) acc[b] = 0.0f;
    const int stride = gridDim.x * blockDim.x;
    const size_t bstride = (size_t)NVERT * 3;
    for (int e = blockIdx.x * blockDim.x + threadIdx.x; e < E; e += stride) {
        const int s = src[e] * 3;
        const int d = dst[e] * 3;
#pragma unroll
        for (int b = 0; b < NBATCH; ++b) {
            const float* __restrict__ xb  = x  + b * bstride;
            const float* __restrict__ dxb = dx + b * bstride;
            float ex0 = xb[d] - xb[s], ex1 = xb[d+1] - xb[s+1], ex2 = xb[d+2] - xb[s+2];
            float ed0 = dxb[d] - dxb[s], ed1 = dxb[d+1] - dxb[s+1], ed2 = dxb[d+2] - dxb[s+2];
            acc[b] += fabsf(ex0*ex0 + ex1*ex1 + ex2*ex2 - (ed0*ed0 + ed1*ed1 + ed2*ed2));
        }
    }
#pragma unroll
    for (int b = 0; b < NBATCH; ++b)
#pragma unroll
        for (int off = 32; off > 0; off >>= 1)
            acc[b] += __shfl_down(acc[b], off, 64);
    __shared__ float red[4][NBATCH];
    const int wave = threadIdx.x >> 6;
    const int lane = threadIdx.x & 63;
    if (lane == 0)
#pragma unroll
        for (int b = 0; b < NBATCH; ++b) red[wave][b] = acc[b];
    __syncthreads();
    if (threadIdx.x == 0)
#pragma unroll
        for (int b = 0; b < NBATCH; ++b)
            atomicAdd(&out[b], (red[0][b] + red[1][b] + red[2][b] + red[3][b]) * invE);
}

extern "C" void kernel_launch(void* const* d_in, const int* in_sizes, int n_in,
                              void* d_out, int out_size, void* d_ws, size_t ws_size,
                              hipStream_t stream) {
    const float* dx = (const float*)d_in[0];
    const float* x  = (const float*)d_in[1];
    const int* edge_src = (const int*)d_in[2];
    const int* edge_dst = (const int*)d_in[3];
    float* out = (float*)d_out;

    const int E = in_sizes[2];
    const float invE = 1.0f / (float)E;
    const size_t need = (size_t)NBATCH * NVERT * 2 * sizeof(float4);  // 25.6 MB

    hipMemsetAsync(d_out, 0, NBATCH * sizeof(float), stream);

    if (ws_size >= need) {
        float4* recs = (float4*)d_ws;
        const int pack_threads = 256;
        const int pack_blocks = (NBATCH * NVERT + pack_threads - 1) / pack_threads;
        arap_pack_kernel<<<pack_blocks, pack_threads, 0, stream>>>(dx, x, recs);

        // 2048 blocks: 256 per batch; batch = blockIdx&7 keeps each batch on
        // one XCD under round-robin dispatch -> 3.2MB slice fits 4MiB L2.
        arap_edge_packed_kernel<<<2048, 256, 0, stream>>>(recs, edge_src, edge_dst,
                                                          out, E, invE);
    } else {
        int blocks = (E + 255) / 256;
        if (blocks > 2048) blocks = 2048;
        arap_edge_kernel<<<blocks, 256, 0, stream>>>(dx, x, edge_src, edge_dst,
                                                     out, E, invE);
    }
}